// Round 1
// baseline (3499.025 us; speedup 1.0000x reference)
//
#include <hip/hip_runtime.h>
#include <math.h>

#define T 1024
#define D 768
#define H 12
#define HD 64
#define FF 3072
#define V 8192
#define EPS 1e-5f

// ---------------- LayerNorm over D=768 of (a[t]+b[t]) ----------------
__global__ void ln_kernel(const float* __restrict__ a, const float* __restrict__ b,
                          const float* __restrict__ w, const float* __restrict__ bias,
                          float* __restrict__ out) {
    int t = blockIdx.x;
    int tid = threadIdx.x;
    __shared__ float red[256];
    float x[3];
    float s = 0.f;
#pragma unroll
    for (int k = 0; k < 3; k++) {
        int d = tid + k * 256;
        x[k] = a[t * D + d] + b[t * D + d];
        s += x[k];
    }
    red[tid] = s; __syncthreads();
    for (int o = 128; o > 0; o >>= 1) { if (tid < o) red[tid] += red[tid + o]; __syncthreads(); }
    float mu = red[0] / (float)D;
    __syncthreads();
    float sq = 0.f;
#pragma unroll
    for (int k = 0; k < 3; k++) { float dx = x[k] - mu; sq += dx * dx; }
    red[tid] = sq; __syncthreads();
    for (int o = 128; o > 0; o >>= 1) { if (tid < o) red[tid] += red[tid + o]; __syncthreads(); }
    float rstd = rsqrtf(red[0] / (float)D + EPS);
#pragma unroll
    for (int k = 0; k < 3; k++) {
        int d = tid + k * 256;
        out[t * D + d] = (x[k] - mu) * rstd * w[d] + bias[d];
    }
}

// ---------------- generic tiled fp32 GEMM: C = A * (BT ? B^T : B) + bias ----
// A: [M,K] row-major. BT: B is [N,K]; else B is [K,N]. 64x64 tile, 4x4/thread.
// All of M, N multiples of 64; K multiple of 16.
template <bool BT, bool GELU>
__global__ void gemm_kernel(const float* __restrict__ A, const float* __restrict__ B,
                            const float* __restrict__ bias, float* __restrict__ C,
                            int M, int N, int K,
                            long long sA, long long sB, long long sBias, long long sC) {
    const int b = blockIdx.z;
    A += (long long)b * sA;
    B += (long long)b * sB;
    C += (long long)b * sC;
    if (bias) bias += (long long)b * sBias;
    const int n0 = blockIdx.x * 64, m0 = blockIdx.y * 64;
    const int tx = threadIdx.x, ty = threadIdx.y;  // 16x16
    const int tid = ty * 16 + tx;
    __shared__ float As[16][65];
    __shared__ float Bs[16][65];
    float acc[4][4] = {};
    for (int k0 = 0; k0 < K; k0 += 16) {
        {
            int m = tid >> 2, k4 = (tid & 3) * 4;
            const float* p = A + (long long)(m0 + m) * K + k0 + k4;
#pragma unroll
            for (int j = 0; j < 4; j++) As[k4 + j][m] = p[j];
        }
        if constexpr (BT) {
            int n = tid >> 2, k4 = (tid & 3) * 4;
            const float* p = B + (long long)(n0 + n) * K + k0 + k4;
#pragma unroll
            for (int j = 0; j < 4; j++) Bs[k4 + j][n] = p[j];
        } else {
            int k = tid >> 4, n4 = (tid & 15) * 4;
            const float* p = B + (long long)(k0 + k) * N + n0 + n4;
#pragma unroll
            for (int j = 0; j < 4; j++) Bs[k][n4 + j] = p[j];
        }
        __syncthreads();
#pragma unroll
        for (int kk = 0; kk < 16; kk++) {
            float av[4], bv[4];
#pragma unroll
            for (int i = 0; i < 4; i++) av[i] = As[kk][ty * 4 + i];
#pragma unroll
            for (int i = 0; i < 4; i++) bv[i] = Bs[kk][tx * 4 + i];
#pragma unroll
            for (int i = 0; i < 4; i++)
#pragma unroll
                for (int j = 0; j < 4; j++)
                    acc[i][j] += av[i] * bv[j];
        }
        __syncthreads();
    }
#pragma unroll
    for (int i = 0; i < 4; i++) {
        int m = m0 + ty * 4 + i;
#pragma unroll
        for (int j = 0; j < 4; j++) {
            int n = n0 + tx * 4 + j;
            float c = acc[i][j];
            if (bias) c += bias[n];
            if (GELU) c = 0.5f * c * (1.0f + erff(c * 0.70710678118654752f));
            C[(long long)m * N + n] = c;
        }
    }
}

// ---------------- v = v_fact (HxH) applied per position to xt heads ----------
__global__ void vmix_kernel(const float* __restrict__ xt, const float* __restrict__ vf,
                            float* __restrict__ v) {
    int t = blockIdx.x, tid = threadIdx.x;
    __shared__ float f[144];
    if (tid < 144) f[tid] = vf[tid];
    __syncthreads();
#pragma unroll
    for (int k = 0; k < 3; k++) {
        int o = tid + k * 256;
        int i = o >> 6, d = o & 63;
        float acc = 0.f;
#pragma unroll
        for (int j = 0; j < 12; j++) acc += f[i * 12 + j] * xt[t * D + j * 64 + d];
        v[((long long)i * T + t) * 64 + d] = acc;  // [H,T,HD]
    }
}

// ---------------- causal attention with alibi; one block per (t,h) ----------
__global__ void attn_kernel(const float* __restrict__ qk, const float* __restrict__ v,
                            float* __restrict__ y) {
    const int t = blockIdx.x, h = blockIdx.y, tid = threadIdx.x;
    __shared__ float qs[64];
    __shared__ float ps[1024];
    __shared__ float red[256];
    if (tid < 64) qs[tid] = qk[t * 1536 + h * 64 + tid];
    __syncthreads();
    float slope = (h < 8) ? exp2f(-(float)(h + 1)) : exp2f(-0.5f * (float)(h - 7));
    const float scale = 0.125f;  // 1/sqrt(64)
    float lmax = -INFINITY;
    for (int j = tid; j <= t; j += 256) {
        const float* kr = qk + j * 1536 + 768 + h * 64;
        float dot = 0.f;
        for (int d2 = 0; d2 < 64; d2++) dot += qs[d2] * kr[d2];
        float s = dot * scale + slope * (float)(j - t);
        ps[j] = s;
        lmax = fmaxf(lmax, s);
    }
    red[tid] = lmax; __syncthreads();
    for (int o = 128; o > 0; o >>= 1) { if (tid < o) red[tid] = fmaxf(red[tid], red[tid + o]); __syncthreads(); }
    float m = red[0]; __syncthreads();
    float lsum = 0.f;
    for (int j = tid; j <= t; j += 256) {
        float e = expf(ps[j] - m);
        ps[j] = e;
        lsum += e;
    }
    red[tid] = lsum; __syncthreads();
    for (int o = 128; o > 0; o >>= 1) { if (tid < o) red[tid] += red[tid + o]; __syncthreads(); }
    float inv = 1.0f / red[0];
    __syncthreads();
    int d = tid & 63, part = tid >> 6;
    float acc = 0.f;
    for (int j = part; j <= t; j += 4) acc += ps[j] * v[((long long)h * T + j) * 64 + d];
    red[tid] = acc; __syncthreads();
    if (tid < 64) {
        float tot = red[tid] + red[tid + 64] + red[tid + 128] + red[tid + 192];
        y[t * D + h * 64 + tid] = tot * inv;  // [T,H,HD]
    }
}

// ---------------- out_fact mix + residual -> xt_new ----------
__global__ void outmix_kernel(const float* __restrict__ xt, const float* __restrict__ y,
                              const float* __restrict__ of, float* __restrict__ out) {
    int t = blockIdx.x, tid = threadIdx.x;
    __shared__ float f[144];
    if (tid < 144) f[tid] = of[tid];
    __syncthreads();
#pragma unroll
    for (int k = 0; k < 3; k++) {
        int o = tid + k * 256;
        int i = o >> 6, d = o & 63;
        float acc = 0.f;
#pragma unroll
        for (int j = 0; j < 12; j++) acc += f[i * 12 + j] * y[t * D + j * 64 + d];
        out[t * D + o] = xt[t * D + o] + acc;
    }
}

// ---------------- per-head LayerNorm over HD=64; one wave per row ----------
__global__ void headln_kernel(const float* __restrict__ in, const float* __restrict__ w,
                              const float* __restrict__ b, float* __restrict__ out) {
    int r = blockIdx.x;      // [0, H*T)
    int lane = threadIdx.x;  // 64
    int h = r >> 10;
    float x = in[r * 64 + lane];
    float s = x;
    for (int o = 32; o > 0; o >>= 1) s += __shfl_xor(s, o);
    float mu = s * (1.0f / 64.0f);
    float dx = x - mu;
    float q = dx * dx;
    for (int o = 32; o > 0; o >>= 1) q += __shfl_xor(q, o);
    float rstd = rsqrtf(q * (1.0f / 64.0f) + EPS);
    out[r * 64 + lane] = dx * rstd * w[h * 64 + lane] + b[h * 64 + lane];
}

// ---------------- row softmax over V=8192, in place ----------
__global__ void softmax_kernel(float* __restrict__ p) {
    long long row = blockIdx.x;
    float* x = p + row * V;
    int tid = threadIdx.x;
    __shared__ float red[256];
    float lm = -INFINITY;
    for (int i = tid; i < V; i += 256) lm = fmaxf(lm, x[i]);
    red[tid] = lm; __syncthreads();
    for (int o = 128; o > 0; o >>= 1) { if (tid < o) red[tid] = fmaxf(red[tid], red[tid + o]); __syncthreads(); }
    float m = red[0]; __syncthreads();
    float ls = 0.f;
    for (int i = tid; i < V; i += 256) { float e = expf(x[i] - m); x[i] = e; ls += e; }
    red[tid] = ls; __syncthreads();
    for (int o = 128; o > 0; o >>= 1) { if (tid < o) red[tid] += red[tid + o]; __syncthreads(); }
    float inv = 1.0f / red[0];
    for (int i = tid; i < V; i += 256) x[i] *= inv;
}

// ---------------- loss (mean sq diff) + xe_new ----------
__global__ void loss_xe_kernel(const float* __restrict__ xhat, const float* __restrict__ xrec,
                               const float* __restrict__ xe, float* __restrict__ out_xe,
                               float* __restrict__ loss) {
    int i = blockIdx.x * 256 + threadIdx.x;  // [0, H*T*HD)
    float a = xhat[i], r = xrec[i];
    float df = a - r;
    int h = i >> 16;          // / (T*HD)
    int t = (i >> 6) & 1023;
    int dd = i & 63;
    int oe = t * D + h * 64 + dd;
    out_xe[oe] = xe[oe] + r;
    __shared__ float red[256];
    red[threadIdx.x] = df * df; __syncthreads();
    for (int o = 128; o > 0; o >>= 1) { if (threadIdx.x < o) red[threadIdx.x] += red[threadIdx.x + o]; __syncthreads(); }
    if (threadIdx.x == 0) atomicAdd(loss, red[0] * (1.0f / 786432.0f));
}

extern "C" void kernel_launch(void* const* d_in, const int* in_sizes, int n_in,
                              void* d_out, int out_size, void* d_ws, size_t ws_size,
                              hipStream_t stream) {
    const float* xt = (const float*)d_in[0];
    const float* xe = (const float*)d_in[1];
    const float* ln1_w = (const float*)d_in[2];
    const float* ln1_b = (const float*)d_in[3];
    const float* qk_w = (const float*)d_in[4];
    const float* qk_b = (const float*)d_in[5];
    const float* v_fact = (const float*)d_in[6];
    const float* out_fact = (const float*)d_in[7];
    const float* ln2_w = (const float*)d_in[8];
    const float* ln2_b = (const float*)d_in[9];
    const float* fc_w = (const float*)d_in[10];
    const float* fc_b = (const float*)d_in[11];
    const float* proj_w = (const float*)d_in[12];
    const float* proj_b = (const float*)d_in[13];
    const float* dln_w = (const float*)d_in[14];
    const float* dln_b = (const float*)d_in[15];
    const float* dict_emb = (const float*)d_in[16];

    float* out_xt = (float*)d_out;
    float* out_xe = out_xt + (long long)T * D;                 // 786432
    float* out_dw = out_xe + (long long)T * D;                 // dict_weights region, 100663296 floats
    float* out_loss = out_dw + (long long)H * T * V;

    // h [H,T,FF] = 37,748,736 floats lives at the start of the dict_weights
    // region (dead until logits overwrite it). Small pre-FFN temporaries live
    // after it. Only xhat/xrec must survive while out_dw is written -> d_ws.
    float* hbuf = out_dw;
    float* scratch = out_dw + (long long)H * T * FF;           // 37,748,736
    float* xnorm = scratch;                                    // 786432
    float* qkbuf = xnorm + 786432;                             // 1572864
    float* vbuf  = qkbuf + 1572864;                            // 786432
    float* ybuf  = vbuf + 786432;                              // 786432
    float* x2    = ybuf + 786432;                              // 786432
    float* hproj = x2 + 786432;                                // 786432
    float* xhat = (float*)d_ws;                                // 786432
    float* xrec = xhat + 786432;                               // 786432

    hipMemsetAsync(out_loss, 0, sizeof(float), stream);

    // 1) ln1(xt + xe)
    ln_kernel<<<T, 256, 0, stream>>>(xt, xe, ln1_w, ln1_b, xnorm);
    // 2) qk = xnorm @ qk_w^T + qk_b   [1024,1536]
    gemm_kernel<true, false><<<dim3(1536 / 64, T / 64, 1), dim3(16, 16), 0, stream>>>(
        xnorm, qk_w, qk_b, qkbuf, T, 1536, D, 0, 0, 0, 0);
    // 3) v = v_fact mix of xt heads   [H,T,HD]
    vmix_kernel<<<T, 256, 0, stream>>>(xt, v_fact, vbuf);
    // 4) attention -> y [T,H,HD]
    attn_kernel<<<dim3(T, H), 256, 0, stream>>>(qkbuf, vbuf, ybuf);
    // 5) xt_new = xt + out_fact mix of y
    outmix_kernel<<<T, 256, 0, stream>>>(xt, ybuf, out_fact, out_xt);
    // 6) ln2(xt_new + xe)
    ln_kernel<<<T, 256, 0, stream>>>(out_xt, xe, ln2_w, ln2_b, x2);
    // 7) h = gelu(x2 @ fc_w^T + fc_b) per head  [H,T,FF]
    gemm_kernel<true, true><<<dim3(FF / 64, T / 64, H), dim3(16, 16), 0, stream>>>(
        x2, fc_w, fc_b, hbuf, T, FF, D,
        0, (long long)FF * D, FF, (long long)T * FF);
    // 8) hproj = h @ proj_w^T + proj_b  [H,T,HD]
    gemm_kernel<true, false><<<dim3(1, T / 64, H), dim3(16, 16), 0, stream>>>(
        hbuf, proj_w, proj_b, hproj, T, HD, FF,
        (long long)T * FF, (long long)HD * FF, HD, (long long)T * HD);
    // 9) x_hat = per-head LN(hproj)
    headln_kernel<<<H * T, 64, 0, stream>>>(hproj, dln_w, dln_b, xhat);
    // 10) logits = x_hat @ dict_emb^T  [H,T,V] (overwrites h region)
    gemm_kernel<true, false><<<dim3(V / 64, T / 64, H), dim3(16, 16), 0, stream>>>(
        xhat, dict_emb, nullptr, out_dw, T, V, HD,
        (long long)T * HD, (long long)V * HD, 0, (long long)T * V);
    // 11) softmax rows -> dict_weights (in place, final output)
    softmax_kernel<<<H * T, 256, 0, stream>>>(out_dw);
    // 12) x_recon = dict_weights @ dict_emb  [H,T,HD]
    gemm_kernel<false, false><<<dim3(1, T / 64, H), dim3(16, 16), 0, stream>>>(
        out_dw, dict_emb, nullptr, xrec, T, HD, V,
        (long long)T * V, (long long)V * HD, 0, (long long)T * HD);
    // 13) dict_loss + xe_new
    loss_xe_kernel<<<(H * T * HD) / 256, 256, 0, stream>>>(xhat, xrec, xe, out_xe, out_loss);
}

// Round 2
// 1512.268 us; speedup vs baseline: 2.3138x; 2.3138x over previous
//
#include <hip/hip_runtime.h>
#include <math.h>

#define T 1024
#define D 768
#define H 12
#define HD 64
#define FF 3072
#define V 8192
#define EPS 1e-5f

typedef float float4e __attribute__((ext_vector_type(4)));
typedef short short8 __attribute__((ext_vector_type(8)));

__device__ __forceinline__ unsigned short f2bf(float f) {
    unsigned int u = __float_as_uint(f);
    unsigned int r = u + 0x7fffu + ((u >> 16) & 1u);
    return (unsigned short)(r >> 16);
}
__device__ __forceinline__ int imin(int a, int b) { return a < b ? a : b; }

#define GLL16(g, l)                                                                        \
    __builtin_amdgcn_global_load_lds((const __attribute__((address_space(1))) void*)(g),   \
                                     (__attribute__((address_space(3))) void*)(l), 16, 0, 0)

// ---------------- fp32 -> bf16 convert ----------------
__global__ void cvt_kernel(const float* __restrict__ in, unsigned short* __restrict__ out,
                           long long n) {
    long long i = ((long long)blockIdx.x * 256 + threadIdx.x) * 4;
    if (i + 3 < n) {
        float4e v = *(const float4e*)(in + i);
        out[i + 0] = f2bf(v[0]);
        out[i + 1] = f2bf(v[1]);
        out[i + 2] = f2bf(v[2]);
        out[i + 3] = f2bf(v[3]);
    }
}

// ---------------- LayerNorm over D=768 of (a+b), bf16 out ----------------
__global__ void ln_kernel(const float* __restrict__ a, const float* __restrict__ b,
                          const float* __restrict__ w, const float* __restrict__ bias,
                          unsigned short* __restrict__ out) {
    int t = blockIdx.x;
    int tid = threadIdx.x;
    __shared__ float red[256];
    float x[3];
    float s = 0.f;
#pragma unroll
    for (int k = 0; k < 3; k++) {
        int d = tid + k * 256;
        x[k] = a[t * D + d] + b[t * D + d];
        s += x[k];
    }
    red[tid] = s; __syncthreads();
    for (int o = 128; o > 0; o >>= 1) { if (tid < o) red[tid] += red[tid + o]; __syncthreads(); }
    float mu = red[0] / (float)D;
    __syncthreads();
    float sq = 0.f;
#pragma unroll
    for (int k = 0; k < 3; k++) { float dx = x[k] - mu; sq += dx * dx; }
    red[tid] = sq; __syncthreads();
    for (int o = 128; o > 0; o >>= 1) { if (tid < o) red[tid] += red[tid + o]; __syncthreads(); }
    float rstd = rsqrtf(red[0] / (float)D + EPS);
#pragma unroll
    for (int k = 0; k < 3; k++) {
        int d = tid + k * 256;
        out[t * D + d] = f2bf((x[k] - mu) * rstd * w[d] + bias[d]);
    }
}

// =====================================================================
// MFMA GEMM: C[M,N] = A[M,K] * B^T (+bias, +gelu). 128x128 tile, BK=32.
// AM: 0 = A fp32 (reg-stage + cvt), 1 = A bf16 (global_load_lds x16)
// BM: 0 = B fp32 [N,K], 1 = B bf16 [N,K] (global_load_lds), 2 = B fp32 [K,N]
// CB: store bf16. ATOM: atomicAdd fp32 (split-K / masked N). BIAS.
// grid.x = nTiles * kChunks, grid.y = M/128, grid.z = batch.
// =====================================================================
template <int AM, int BM, bool GELU_, bool CB, bool ATOM, bool BIAS>
__global__ __launch_bounds__(256, 2)
void mfma_gemm(const void* __restrict__ Av, const void* __restrict__ Bv,
               const float* __restrict__ bias, void* __restrict__ Cv,
               int M, int N, int K, int lda, int ldb, int ldc,
               long long sA, long long sB, long long sBias, long long sC,
               int nTiles, int kLen) {
    const int bz = blockIdx.z;
    const int nt = blockIdx.x % nTiles;
    const int kc = blockIdx.x / nTiles;
    const int m0 = blockIdx.y * 128;
    const int n0 = nt * 128;
    const int kBeg = kc * kLen, kEnd = kBeg + kLen;

    const int tid = threadIdx.x;
    const int lane = tid & 63;
    const int w = tid >> 6;
    const int wm = w >> 1, wn = w & 1;

    __shared__ __align__(16) unsigned short Asb[128 * 32];
    __shared__ __align__(16) unsigned short Bs[128 * 32];

    float4e acc[4][4];
#pragma unroll
    for (int i = 0; i < 4; i++)
#pragma unroll
        for (int j = 0; j < 4; j++) acc[i][j] = (float4e){0.f, 0.f, 0.f, 0.f};

    const int q = lane >> 4, r = lane & 15;

    for (int k0 = kBeg; k0 < kEnd; k0 += 32) {
        __syncthreads();
        // ---- stage A ----
        if constexpr (AM == 1) {
            const unsigned short* Ab = (const unsigned short*)Av + (long long)bz * sA;
            int rowA = lane >> 2, kg = (lane & 3) * 8;
#pragma unroll
            for (int s = 0; s < 2; s++) {
                int seg = w * 2 + s;
                int rs = seg * 16 + rowA;
                const unsigned short* g = Ab + (long long)(m0 + rs) * lda + k0 + kg;
                GLL16(g, &Asb[seg * 512]);
            }
        } else {
            const float* Af = (const float*)Av + (long long)bz * sA;
            int row = tid >> 1, half = tid & 1;
            const float4e* p = (const float4e*)(Af + (long long)(m0 + row) * lda + k0 + half * 16);
            float4e v0 = p[0], v1 = p[1], v2 = p[2], v3 = p[3];
            short8 s0, s1;
#pragma unroll
            for (int e = 0; e < 4; e++) {
                s0[e] = (short)f2bf(v0[e]); s0[e + 4] = (short)f2bf(v1[e]);
                s1[e] = (short)f2bf(v2[e]); s1[e + 4] = (short)f2bf(v3[e]);
            }
            *(short8*)&Asb[row * 32 + half * 16] = s0;
            *(short8*)&Asb[row * 32 + half * 16 + 8] = s1;
        }
        // ---- stage B ----
        if constexpr (BM == 1) {
            const unsigned short* Bb = (const unsigned short*)Bv + (long long)bz * sB;
            int rowA = lane >> 2, kg = (lane & 3) * 8;
#pragma unroll
            for (int s = 0; s < 2; s++) {
                int seg = w * 2 + s;
                int rs = imin(n0 + seg * 16 + rowA, N - 1);
                const unsigned short* g = Bb + (long long)rs * ldb + k0 + kg;
                GLL16(g, &Bs[seg * 512]);
            }
        } else if constexpr (BM == 0) {
            const float* Bf = (const float*)Bv + (long long)bz * sB;
            int row = tid >> 1, half = tid & 1;
            const float4e* p = (const float4e*)(Bf + (long long)(n0 + row) * ldb + k0 + half * 16);
            float4e v0 = p[0], v1 = p[1], v2 = p[2], v3 = p[3];
            short8 s0, s1;
#pragma unroll
            for (int e = 0; e < 4; e++) {
                s0[e] = (short)f2bf(v0[e]); s0[e + 4] = (short)f2bf(v1[e]);
                s1[e] = (short)f2bf(v2[e]); s1[e + 4] = (short)f2bf(v3[e]);
            }
            *(short8*)&Bs[row * 32 + half * 16] = s0;
            *(short8*)&Bs[row * 32 + half * 16 + 8] = s1;
        } else {  // BM == 2: fp32 [K,N], transpose-stage (N<=64 cols staged)
            const float* Bf = (const float*)Bv + (long long)bz * sB;
            int kk = tid >> 3, nn = (tid & 7) * 8;
            const float4e* p = (const float4e*)(Bf + (long long)(k0 + kk) * ldb + nn);
            float4e v0 = p[0], v1 = p[1];
#pragma unroll
            for (int e = 0; e < 4; e++) {
                Bs[(nn + e) * 32 + kk] = f2bf(v0[e]);
                Bs[(nn + 4 + e) * 32 + kk] = f2bf(v1[e]);
            }
        }
        __syncthreads();
        // ---- fragments + MFMA ----
        short8 af[4], bfr[4];
#pragma unroll
        for (int i = 0; i < 4; i++)
            af[i] = *(const short8*)&Asb[(wm * 64 + i * 16 + r) * 32 + q * 8];
#pragma unroll
        for (int j = 0; j < 4; j++)
            bfr[j] = *(const short8*)&Bs[(wn * 64 + j * 16 + r) * 32 + q * 8];
#pragma unroll
        for (int i = 0; i < 4; i++)
#pragma unroll
            for (int j = 0; j < 4; j++)
                acc[i][j] = __builtin_amdgcn_mfma_f32_16x16x32_bf16(af[i], bfr[j], acc[i][j], 0, 0, 0);
    }

    // ---- epilogue ----
    float* Cf = (float*)Cv + (long long)bz * sC;
    unsigned short* Cb = (unsigned short*)Cv + (long long)bz * sC;
    if (BIAS) bias += (long long)bz * sBias;
#pragma unroll
    for (int j = 0; j < 4; j++) {
        int n = n0 + wn * 64 + j * 16 + r;
        if (n >= N) continue;
        float bj = BIAS ? bias[n] : 0.f;
#pragma unroll
        for (int i = 0; i < 4; i++) {
            int mb = m0 + wm * 64 + i * 16 + q * 4;
#pragma unroll
            for (int rr = 0; rr < 4; rr++) {
                float v2 = acc[i][j][rr] + bj;
                if (GELU_) v2 = 0.5f * v2 * (1.0f + erff(v2 * 0.70710678118654752f));
                long long idx = (long long)(mb + rr) * ldc + n;
                if (ATOM) atomicAdd(&Cf[idx], v2);
                else if (CB) Cb[idx] = f2bf(v2);
                else Cf[idx] = v2;
            }
        }
    }
}

// ---------------- v = v_fact (HxH) applied per position to xt heads ----------
__global__ void vmix_kernel(const float* __restrict__ xt, const float* __restrict__ vf,
                            float* __restrict__ v) {
    int t = blockIdx.x, tid = threadIdx.x;
    __shared__ float f[144];
    if (tid < 144) f[tid] = vf[tid];
    __syncthreads();
#pragma unroll
    for (int k = 0; k < 3; k++) {
        int o = tid + k * 256;
        int i = o >> 6, d = o & 63;
        float acc = 0.f;
#pragma unroll
        for (int j = 0; j < 12; j++) acc += f[i * 12 + j] * xt[t * D + j * 64 + d];
        v[((long long)i * T + t) * 64 + d] = acc;  // [H,T,HD]
    }
}

// ---------------- causal attention with alibi; one block per (t,h) ----------
__global__ void attn_kernel(const float* __restrict__ qk, const float* __restrict__ v,
                            float* __restrict__ y) {
    const int t = blockIdx.x, h = blockIdx.y, tid = threadIdx.x;
    __shared__ float4e qs4[16];
    __shared__ float ps[1024];
    __shared__ float red[256];
    if (tid < 16) qs4[tid] = *(const float4e*)(qk + t * 1536 + h * 64 + tid * 4);
    __syncthreads();
    float slope = (h < 8) ? exp2f(-(float)(h + 1)) : exp2f(-0.5f * (float)(h - 7));
    const float scale = 0.125f;
    float lmax = -INFINITY;
    for (int j = tid; j <= t; j += 256) {
        const float4e* kr = (const float4e*)(qk + j * 1536 + 768 + h * 64);
        float dot = 0.f;
#pragma unroll
        for (int d4 = 0; d4 < 16; d4++) {
            float4e a = qs4[d4], b = kr[d4];
            dot += a[0] * b[0] + a[1] * b[1] + a[2] * b[2] + a[3] * b[3];
        }
        float s = dot * scale + slope * (float)(j - t);
        ps[j] = s;
        lmax = fmaxf(lmax, s);
    }
    red[tid] = lmax; __syncthreads();
    for (int o = 128; o > 0; o >>= 1) { if (tid < o) red[tid] = fmaxf(red[tid], red[tid + o]); __syncthreads(); }
    float m = red[0]; __syncthreads();
    float lsum = 0.f;
    for (int j = tid; j <= t; j += 256) {
        float e = expf(ps[j] - m);
        ps[j] = e;
        lsum += e;
    }
    red[tid] = lsum; __syncthreads();
    for (int o = 128; o > 0; o >>= 1) { if (tid < o) red[tid] += red[tid + o]; __syncthreads(); }
    float inv = 1.0f / red[0];
    __syncthreads();
    int d = tid & 63, part = tid >> 6;
    float acc = 0.f;
    for (int j = part; j <= t; j += 4) acc += ps[j] * v[((long long)h * T + j) * 64 + d];
    red[tid] = acc; __syncthreads();
    if (tid < 64) {
        float tot = red[tid] + red[tid + 64] + red[tid + 128] + red[tid + 192];
        y[t * D + h * 64 + tid] = tot * inv;  // [T,H,HD]
    }
}

// ---------------- out_fact mix + residual -> xt_new ----------
__global__ void outmix_kernel(const float* __restrict__ xt, const float* __restrict__ y,
                              const float* __restrict__ of, float* __restrict__ out) {
    int t = blockIdx.x, tid = threadIdx.x;
    __shared__ float f[144];
    if (tid < 144) f[tid] = of[tid];
    __syncthreads();
#pragma unroll
    for (int k = 0; k < 3; k++) {
        int o = tid + k * 256;
        int i = o >> 6, d = o & 63;
        float acc = 0.f;
#pragma unroll
        for (int j = 0; j < 12; j++) acc += f[i * 12 + j] * y[t * D + j * 64 + d];
        out[t * D + o] = xt[t * D + o] + acc;
    }
}

// ---------------- per-head LN over HD=64 of (hproj + proj_b); fp32 out ------
__global__ void headln_kernel(const float* __restrict__ in, const float* __restrict__ pb,
                              const float* __restrict__ w, const float* __restrict__ b,
                              float* __restrict__ out) {
    int rrow = blockIdx.x;   // [0, H*T)
    int lane = threadIdx.x;  // 64
    int h = rrow >> 10;
    float x = in[rrow * 64 + lane] + pb[h * 64 + lane];
    float s = x;
    for (int o = 32; o > 0; o >>= 1) s += __shfl_xor(s, o);
    float mu = s * (1.0f / 64.0f);
    float dx = x - mu;
    float qv = dx * dx;
    for (int o = 32; o > 0; o >>= 1) qv += __shfl_xor(qv, o);
    float rstd = rsqrtf(qv * (1.0f / 64.0f) + EPS);
    out[rrow * 64 + lane] = dx * rstd * w[h * 64 + lane] + b[h * 64 + lane];
}

// ---------------- row softmax over V=8192, in place, float4 ----------
__global__ void softmax_kernel(float* __restrict__ p) {
    long long row = blockIdx.x;
    float4e* x = (float4e*)(p + row * V);
    int tid = threadIdx.x;
    __shared__ float red[256];
    float lm = -INFINITY;
#pragma unroll
    for (int k = 0; k < 8; k++) {
        float4e v = x[tid + k * 256];
        lm = fmaxf(lm, fmaxf(fmaxf(v[0], v[1]), fmaxf(v[2], v[3])));
    }
    red[tid] = lm; __syncthreads();
    for (int o = 128; o > 0; o >>= 1) { if (tid < o) red[tid] = fmaxf(red[tid], red[tid + o]); __syncthreads(); }
    float m = red[0]; __syncthreads();
    float ls = 0.f;
#pragma unroll
    for (int k = 0; k < 8; k++) {
        float4e v = x[tid + k * 256];
        v[0] = expf(v[0] - m); v[1] = expf(v[1] - m);
        v[2] = expf(v[2] - m); v[3] = expf(v[3] - m);
        x[tid + k * 256] = v;
        ls += v[0] + v[1] + v[2] + v[3];
    }
    red[tid] = ls; __syncthreads();
    for (int o = 128; o > 0; o >>= 1) { if (tid < o) red[tid] += red[tid + o]; __syncthreads(); }
    float inv = 1.0f / red[0];
#pragma unroll
    for (int k = 0; k < 8; k++) {
        float4e v = x[tid + k * 256];
        v[0] *= inv; v[1] *= inv; v[2] *= inv; v[3] *= inv;
        x[tid + k * 256] = v;
    }
}

// ---------------- loss (mean sq diff) + xe_new ----------
__global__ void loss_xe_kernel(const float* __restrict__ xhat, const float* __restrict__ xrec,
                               const float* __restrict__ xe, float* __restrict__ out_xe,
                               float* __restrict__ loss) {
    int i = blockIdx.x * 256 + threadIdx.x;
    float a = xhat[i], r = xrec[i];
    float df = a - r;
    int h = i >> 16;
    int t = (i >> 6) & 1023;
    int dd = i & 63;
    int oe = t * D + h * 64 + dd;
    out_xe[oe] = xe[oe] + r;
    __shared__ float red[256];
    red[threadIdx.x] = df * df; __syncthreads();
    for (int o = 128; o > 0; o >>= 1) { if (threadIdx.x < o) red[threadIdx.x] += red[threadIdx.x + o]; __syncthreads(); }
    if (threadIdx.x == 0) atomicAdd(loss, red[0] * (1.0f / 786432.0f));
}

extern "C" void kernel_launch(void* const* d_in, const int* in_sizes, int n_in,
                              void* d_out, int out_size, void* d_ws, size_t ws_size,
                              hipStream_t stream) {
    const float* xt = (const float*)d_in[0];
    const float* xe = (const float*)d_in[1];
    const float* ln1_w = (const float*)d_in[2];
    const float* ln1_b = (const float*)d_in[3];
    const float* qk_w = (const float*)d_in[4];
    const float* qk_b = (const float*)d_in[5];
    const float* v_fact = (const float*)d_in[6];
    const float* out_fact = (const float*)d_in[7];
    const float* ln2_w = (const float*)d_in[8];
    const float* ln2_b = (const float*)d_in[9];
    const float* fc_w = (const float*)d_in[10];
    const float* fc_b = (const float*)d_in[11];
    const float* proj_w = (const float*)d_in[12];
    const float* proj_b = (const float*)d_in[13];
    const float* dln_w = (const float*)d_in[14];
    const float* dln_b = (const float*)d_in[15];
    const float* dict_emb = (const float*)d_in[16];

    float* out_xt = (float*)d_out;
    float* out_xe = out_xt + (long long)T * D;
    float* out_dw = out_xe + (long long)T * D;               // [H,T,V] fp32, 100663296 floats
    float* out_loss = out_dw + (long long)H * T * V;

    // Scratch inside the (dead-until-logits) dict_weights region.
    // hbuf at the start; everything else after it so the fc GEMM's writes
    // don't overlap its own inputs. All offsets multiple of 4 floats (16B).
    unsigned short* hbuf = (unsigned short*)out_dw;          // [H,T,FF] bf16 = 18874368 floats
    float* sc = out_dw + 18874368;
    unsigned short* fc_wb   = (unsigned short*)(sc);                       // 14155776 f
    unsigned short* qk_wb   = (unsigned short*)(sc + 14155776);            //   589824 f
    unsigned short* proj_wb = (unsigned short*)(sc + 14155776 + 589824);   //  1179648 f
    unsigned short* xnormb  = (unsigned short*)(sc + 15925248);            //   393216 f
    unsigned short* x2b     = (unsigned short*)(sc + 16318464);            //   393216 f
    float* qkbuf = sc + 16711680;                                          //  1572864 f
    float* vbuf  = sc + 18284544;                                          //   786432 f
    float* ybuf  = sc + 19070976;                                          //   786432 f
    float* hproj = sc + 19857408;                                          //   786432 f
    float* xhat = (float*)d_ws;                              // 786432 f
    float* xrec = xhat + 786432;                             // 786432 f

    hipMemsetAsync(out_loss, 0, sizeof(float), stream);
    hipMemsetAsync(hproj, 0, 786432 * sizeof(float), stream);
    hipMemsetAsync(xrec, 0, 786432 * sizeof(float), stream);

    // weight converts
    cvt_kernel<<<27648, 256, 0, stream>>>(fc_w, fc_wb, 28311552LL);
    cvt_kernel<<<1152, 256, 0, stream>>>(qk_w, qk_wb, 1179648LL);
    cvt_kernel<<<2304, 256, 0, stream>>>(proj_w, proj_wb, 2359296LL);

    // 1) ln1(xt+xe) -> bf16
    ln_kernel<<<T, 256, 0, stream>>>(xt, xe, ln1_w, ln1_b, xnormb);
    // 2) v mix
    vmix_kernel<<<T, 256, 0, stream>>>(xt, v_fact, vbuf);
    // 3) qk = xnorm @ qk_w^T + qk_b  [1024,1536] fp32
    mfma_gemm<1, 1, false, false, false, true><<<dim3(12, 8, 1), 256, 0, stream>>>(
        xnormb, qk_wb, qk_b, qkbuf, 1024, 1536, 768, 768, 768, 1536,
        0, 0, 0, 0, 12, 768);
    // 4) attention
    attn_kernel<<<dim3(T, H), 256, 0, stream>>>(qkbuf, vbuf, ybuf);
    // 5) xt_new
    outmix_kernel<<<T, 256, 0, stream>>>(xt, ybuf, out_fact, out_xt);
    // 6) ln2 -> bf16
    ln_kernel<<<T, 256, 0, stream>>>(out_xt, xe, ln2_w, ln2_b, x2b);
    // 7) h = gelu(x2 @ fc_w^T + fc_b) -> bf16  [H,T,FF]
    mfma_gemm<1, 1, true, true, false, true><<<dim3(24, 8, 12), 256, 0, stream>>>(
        x2b, fc_wb, fc_b, hbuf, 1024, 3072, 768, 768, 768, 3072,
        0, (long long)FF * D, FF, (long long)T * FF, 24, 768);
    // 8) hproj = h @ proj_w^T (split-K=2, atomic)  [H,T,64]
    mfma_gemm<1, 1, false, false, true, false><<<dim3(2, 8, 12), 256, 0, stream>>>(
        hbuf, proj_wb, nullptr, hproj, 1024, 64, 3072, 3072, 3072, 64,
        (long long)T * FF, (long long)HD * FF, 0, (long long)T * HD, 1, 1536);
    // 9) x_hat = LN(hproj + proj_b)
    headln_kernel<<<H * T, 64, 0, stream>>>(hproj, proj_b, dln_w, dln_b, xhat);
    // 10) logits = x_hat @ dict_emb^T  [H,T,V]
    mfma_gemm<0, 0, false, false, false, false><<<dim3(64, 8, 12), 256, 0, stream>>>(
        xhat, dict_emb, nullptr, out_dw, 1024, 8192, 64, 64, 64, 8192,
        (long long)T * HD, (long long)V * HD, 0, (long long)T * V, 64, 64);
    // 11) softmax in place
    softmax_kernel<<<H * T, 256, 0, stream>>>(out_dw);
    // 12) x_recon = probs @ dict_emb (split-K=4, atomic)  [H,T,64]
    mfma_gemm<0, 2, false, false, true, false><<<dim3(4, 8, 12), 256, 0, stream>>>(
        out_dw, dict_emb, nullptr, xrec, 1024, 64, 8192, 8192, 64, 64,
        (long long)T * V, (long long)V * HD, 0, (long long)T * HD, 1, 2048);
    // 13) loss + xe_new
    loss_xe_kernel<<<(H * T * HD) / 256, 256, 0, stream>>>(xhat, xrec, xe, out_xe, out_loss);
}